// Round 10
// baseline (174.240 us; speedup 1.0000x reference)
//
#include <hip/hip_runtime.h>

typedef unsigned short u16;
typedef __attribute__((ext_vector_type(8))) short short8;   // 8 bf16 = 4 VGPRs (MFMA A/B frag)
typedef __attribute__((ext_vector_type(4))) float f32x4;    // MFMA C/D frag

static __device__ __forceinline__ u16 f32_to_bf16(float f) {
  unsigned u = __float_as_uint(f);
  u += 0x7fffu + ((u >> 16) & 1u);   // round-to-nearest-even; inputs finite
  return (u16)(u >> 16);
}

// async global->LDS, 16 B per lane; lds base must be wave-uniform, lane i
// lands at base + i*16 (m97/m104 semantics).
static __device__ __forceinline__ void async16(u16* lds, const u16* g) {
  __builtin_amdgcn_global_load_lds(
      (const __attribute__((address_space(1))) void*)g,
      (__attribute__((address_space(3))) void*)lds, 16, 0, 0);
}

// XOR-swizzled LDS tiles: row r (8 chunks of 16B), logical chunk c at physical
// c ^ (r&7).  Staging lane uses global chunk (lane&7)^(lane>>3); reads XOR the
// chunk index with lo&7.  Conflict-free (R6-verified: 1.35e7 -> 5.4e5).

// ---------------------------------------------------------------------------
// Kernel 0 (merged prep): id<2048 -> fp32->bf16 convert of x (8 elem/thread);
// id>=2048 -> weight transpose+convert.
// ---------------------------------------------------------------------------
__global__ void __launch_bounds__(256) prep_kernel(
    const float* __restrict__ x,
    const float* __restrict__ Wq, const float* __restrict__ Wk,
    const float* __restrict__ Wv, const float* __restrict__ Wo,
    u16* __restrict__ Xb, u16* __restrict__ WqT, u16* __restrict__ WkvT,
    u16* __restrict__ WoT) {
  __shared__ u16 T[64][72];
  int id = blockIdx.x;
  int tid = threadIdx.x;
  if (id < 2048) {                       // convert role
    int base = (id * 256 + tid) * 8;
    float4 a = *(const float4*)&x[base];
    float4 b = *(const float4*)&x[base + 4];
    short8 v;
    v[0] = (short)f32_to_bf16(a.x); v[1] = (short)f32_to_bf16(a.y);
    v[2] = (short)f32_to_bf16(a.z); v[3] = (short)f32_to_bf16(a.w);
    v[4] = (short)f32_to_bf16(b.x); v[5] = (short)f32_to_bf16(b.y);
    v[6] = (short)f32_to_bf16(b.z); v[7] = (short)f32_to_bf16(b.w);
    *(short8*)&Xb[base] = v;
    return;
  }
  int id2 = id - 2048;                   // transpose role, 0..543
  const float* src; u16* dst; int tk, tn, src_ld, row_off;
  if (id2 < 256)      { src = Wq; dst = WqT;  tk = id2 & 15; tn = id2 >> 4; src_ld = 1024; row_off = 0; }
  else if (id2 < 512) { int i = id2 - 256; src = Wo; dst = WoT; tk = i & 15; tn = i >> 4; src_ld = 1024; row_off = 0; }
  else if (id2 < 528) { src = Wk; dst = WkvT; tk = id2 - 512; tn = 0; src_ld = 64; row_off = 0; }
  else                { src = Wv; dst = WkvT; tk = id2 - 528; tn = 0; src_ld = 64; row_off = 64; }
  int k0 = tk * 64, n0 = tn * 64;
#pragma unroll
  for (int it = 0; it < 2; ++it) {
    int c = tid + it * 256;            // 0..511
    int r = c >> 3, cc = (c & 7) * 8;  // src row (k), col chunk (n)
    const float* p = &src[(k0 + r) * src_ld + n0 + cc];
    float4 a = *(const float4*)&p[0];
    float4 b = *(const float4*)&p[4];
    short8 v;
    v[0] = (short)f32_to_bf16(a.x); v[1] = (short)f32_to_bf16(a.y);
    v[2] = (short)f32_to_bf16(a.z); v[3] = (short)f32_to_bf16(a.w);
    v[4] = (short)f32_to_bf16(b.x); v[5] = (short)f32_to_bf16(b.y);
    v[6] = (short)f32_to_bf16(b.z); v[7] = (short)f32_to_bf16(b.w);
    *(short8*)&T[r][cc] = v;
  }
  __syncthreads();
#pragma unroll
  for (int it = 0; it < 2; ++it) {
    int c = tid + it * 256;
    int r = c >> 3, cc = (c & 7) * 8;  // dst row (n), col chunk (k)
    short8 v;
#pragma unroll
    for (int j = 0; j < 8; ++j) v[j] = (short)T[cc + j][r];
    *(short8*)&dst[(row_off + n0 + r) * 1024 + k0 + cc] = v;
  }
}

// ---------------------------------------------------------------------------
// GEMM 64x64 tile, BK=64, 4 waves (2x2), each wave 2x2 16x16x32 subtiles.
// Double-buffered single-barrier K-loop; XOR-swizzled LDS; DMA staging.
// Small tile -> 1152/1024-block grids (~4.5/CU co-resident): the GEMMs are
// latency-bound (R8 vs R9 evidence), block count is the binding resource.
// ---------------------------------------------------------------------------
__device__ __forceinline__ void stage_64x64(
    const u16* __restrict__ A, const u16* __restrict__ BT, int m0, int K,
    int k0, u16* As, u16* Bs, int w, int lrow, int swz8) {
#pragma unroll
  for (int it = 0; it < 2; ++it) {           // 8 chunk-groups each (64 rows)
    int W = w * 2 + it;
    async16(As + W * 512, &A[(size_t)(m0 + W * 8 + lrow) * K + k0 + swz8]);
    async16(Bs + W * 512, &BT[(size_t)(W * 8 + lrow) * K + k0 + swz8]);
  }
}

__device__ __forceinline__ void gemm_core_64_db(
    const u16* __restrict__ A, const u16* __restrict__ BT, int m0, int K,
    f32x4 (&acc)[2][2], u16* As, u16* Bs,   // each 2 x 64*64 u16
    int lane, int w, int wr, int wc, int g, int lo) {
  int lrow = lane >> 3;
  int swz8 = ((lane & 7) ^ lrow) * 8;
  int lo7 = lo & 7;
  const int NK = K >> 6;
  stage_64x64(A, BT, m0, K, 0, As, Bs, w, lrow, swz8);
  for (int kt = 0; kt < NK; ++kt) {
    int cur = kt & 1;
    __syncthreads();                         // cur ready; nxt free
    if (kt + 1 < NK)
      stage_64x64(A, BT, m0, K, (kt + 1) * 64,
                  As + (cur ^ 1) * 4096, Bs + (cur ^ 1) * 4096, w, lrow, swz8);
    const u16* Asc = As + cur * 4096;
    const u16* Bsc = Bs + cur * 4096;
#pragma unroll
    for (int ks = 0; ks < 2; ++ks) {
      int pc = ((ks * 4 + g) ^ lo7) * 8;     // physical chunk offset
      short8 af[2], bf[2];
#pragma unroll
      for (int i = 0; i < 2; ++i) {
        af[i] = *(const short8*)&Asc[(wr * 32 + i * 16 + lo) * 64 + pc];
        bf[i] = *(const short8*)&Bsc[(wc * 32 + i * 16 + lo) * 64 + pc];
      }
#pragma unroll
      for (int mi = 0; mi < 2; ++mi)
#pragma unroll
        for (int ni = 0; ni < 2; ++ni)
          acc[mi][ni] = __builtin_amdgcn_mfma_f32_16x16x32_bf16(
              af[mi], bf[ni], acc[mi][ni], 0, 0, 0);
    }
  }
}

// ---------------------------------------------------------------------------
// Kernel 2: QKV projection.  grid (64, 18).  nb<16: Q tile (cols nb*64..)
// into Qb [4096][1024] (UNSCALED; Qb = d_out scratch).  nb==16: K into
// KVb [4096][64]; nb==17: V scattered transposed into VTb [2][64][2048].
// ---------------------------------------------------------------------------
__global__ void __launch_bounds__(256) qkv_gemm(
    const u16* __restrict__ Xb, const u16* __restrict__ WqT,
    const u16* __restrict__ WkvT, u16* __restrict__ Qb, u16* __restrict__ KVb,
    u16* __restrict__ VTb) {
  __shared__ u16 As[2 * 64 * 64];
  __shared__ u16 Bs[2 * 64 * 64];
  int tid = threadIdx.x, lane = tid & 63, w = tid >> 6;
  int wr = w >> 1, wc = w & 1, g = lane >> 4, lo = lane & 15;
  int m0 = blockIdx.x * 64, nb = blockIdx.y;
  const u16* BT = (nb < 16) ? (WqT + (size_t)nb * 64 * 1024)
                            : (WkvT + (size_t)(nb - 16) * 64 * 1024);
  f32x4 acc[2][2];
  f32x4 zz = {0.f, 0.f, 0.f, 0.f};
#pragma unroll
  for (int i = 0; i < 2; ++i)
#pragma unroll
    for (int j = 0; j < 2; ++j) acc[i][j] = zz;
  gemm_core_64_db(Xb, BT, m0, 1024, acc, As, Bs, lane, w, wr, wc, g, lo);
#pragma unroll
  for (int mi = 0; mi < 2; ++mi)
#pragma unroll
    for (int ni = 0; ni < 2; ++ni)
#pragma unroll
      for (int r = 0; r < 4; ++r) {
        int row = m0 + wr * 32 + mi * 16 + g * 4 + r;
        int col = wc * 32 + ni * 16 + lo;          // 0..63
        u16 v = f32_to_bf16(acc[mi][ni][r]);
        if (nb < 16) {
          Qb[row * 1024 + nb * 64 + col] = v;
        } else if (nb == 16) {
          KVb[row * 64 + col] = v;                 // K, compact stride 64
        } else {
          VTb[(((row >> 11) * 64) + col) * 2048 + (row & 2047)] = v;  // V^T
        }
      }
}

// ---------------------------------------------------------------------------
// Kernel 3: fused causal flash attention (MQA) — unchanged from R9.
// BQ=64, 4 waves x 16 q-rows; grid (16 h, 32 by-swizzled, 2 b) = 1024 blocks.
// Double-buffered single-barrier KV loop; fixed-offset softmax
// p = exp2(s*0.125*log2e - 11.5416); row-sum l via all-ones-B MFMA;
// Ps stored by truncation (P in [0,1], err <= 2^-8, consistent with l).
// ---------------------------------------------------------------------------
__global__ void __launch_bounds__(256) attn_kernel(
    const u16* __restrict__ Qb, const u16* __restrict__ KVb,
    const u16* __restrict__ VTb, u16* __restrict__ AOb) {
  __shared__ u16 Ks[2][64 * 64];    // K tile [key][d], swizzled
  __shared__ u16 Vt[2][64 * 64];    // V tile [d][key], swizzled
  __shared__ u16 Ps[4][16][72];     // per-wave P [q_local][key], padded
  int tid = threadIdx.x, lane = tid & 63, w = tid >> 6;
  int gq = lane >> 4, lo = lane & 15;
  int h = blockIdx.x;
  int by = blockIdx.y;                      // 0..31
  int qt = (by < 16) ? by : (47 - by);      // load-balance swizzle
  int b = blockIdx.z;
  int q0 = qt * 64;
  int qbase = q0 + w * 16;                  // this wave's first q-row
  int lrow = lane >> 3;
  int swz8 = ((lane & 7) ^ lrow) * 8;
  int lo7 = lo & 7;

  // Q fragments (A-layout): row = lo, k = ks*32 + gq*8 + j
  short8 qf[2];
  {
    const u16* qp = &Qb[(size_t)(b * 2048 + qbase + lo) * 1024 + h * 64];
    qf[0] = *(const short8*)&qp[gq * 8];
    qf[1] = *(const short8*)&qp[32 + gq * 8];
  }

  short8 ones;
#pragma unroll
  for (int j = 0; j < 8; ++j) ones[j] = (short)0x3F80;  // bf16 1.0

  f32x4 zz = {0.f, 0.f, 0.f, 0.f};
  f32x4 oacc[4], l_acc;
#pragma unroll
  for (int i = 0; i < 4; ++i) oacc[i] = zz;
  l_acc = zz;

  const float kExp = 0.18033688011112042f;   // 0.125*log2(e)
  const float kOff = 11.541560327111707f;    // 8*log2(e) fixed offset

  // stage tile t into buffer bu
  auto stage_kv = [&](int t, int bu) {
#pragma unroll
    for (int it = 0; it < 2; ++it) {
      int W = w * 2 + it;
      async16(&Ks[bu][W * 512],
              &KVb[(size_t)(b * 2048 + t * 64 + W * 8 + lrow) * 64 + swz8]);
      async16(&Vt[bu][W * 512],
              &VTb[((size_t)b * 64 + W * 8 + lrow) * 2048 + t * 64 + swz8]);
    }
  };

  int nst = qt + 1;   // causal: keys 0 .. q0+63
  stage_kv(0, 0);
  for (int t = 0; t < nst; ++t) {
    int cur = t & 1;
    __syncthreads();                 // cur ready; nxt free
    if (t + 1 < nst) stage_kv(t + 1, cur ^ 1);
    int k0 = t * 64;

    // S_raw = Q @ K^T
    f32x4 sacc[4];
#pragma unroll
    for (int ns = 0; ns < 4; ++ns) sacc[ns] = zz;
#pragma unroll
    for (int ks = 0; ks < 2; ++ks) {
      int pc = ((ks * 4 + gq) ^ lo7) * 8;
      short8 kf[4];
#pragma unroll
      for (int ns = 0; ns < 4; ++ns)
        kf[ns] = *(const short8*)&Ks[cur][(ns * 16 + lo) * 64 + pc];
#pragma unroll
      for (int ns = 0; ns < 4; ++ns)
        sacc[ns] = __builtin_amdgcn_mfma_f32_16x16x32_bf16(
            qf[ks], kf[ns], sacc[ns], 0, 0, 0);
    }

    // p = exp2(s*kExp - kOff); causal mask p=0 on the diagonal tile
    bool diag = (t == qt);
#pragma unroll
    for (int ns = 0; ns < 4; ++ns)
#pragma unroll
      for (int r = 0; r < 4; ++r) {
        float p = __builtin_amdgcn_exp2f(fmaf(sacc[ns][r], kExp, -kOff));
        if (diag) {
          int qg = qbase + gq * 4 + r;
          int kg = k0 + ns * 16 + lo;
          if (kg > qg) p = 0.f;
        }
        Ps[w][gq * 4 + r][ns * 16 + lo] = (u16)(__float_as_uint(p) >> 16);
      }
    __threadfence_block();   // wave-private Ps: lgkm wait, no block barrier

    // O += P @ V ; l += P @ 1
#pragma unroll
    for (int k2 = 0; k2 < 2; ++k2) {
      short8 pf = *(const short8*)&Ps[w][lo][k2 * 32 + gq * 8];
      int pc = ((k2 * 4 + gq) ^ lo7) * 8;
      short8 vf[4];
#pragma unroll
      for (int ds = 0; ds < 4; ++ds)
        vf[ds] = *(const short8*)&Vt[cur][(ds * 16 + lo) * 64 + pc];
#pragma unroll
      for (int ds = 0; ds < 4; ++ds)
        oacc[ds] = __builtin_amdgcn_mfma_f32_16x16x32_bf16(
            pf, vf[ds], oacc[ds], 0, 0, 0);
      l_acc = __builtin_amdgcn_mfma_f32_16x16x32_bf16(pf, ones, l_acc, 0, 0, 0);
    }
  }

  // epilogue: normalize and store [s][h*64+d] bf16
#pragma unroll
  for (int r = 0; r < 4; ++r) {
    float inv_l = 1.0f / l_acc[r];
    int row = b * 2048 + qbase + gq * 4 + r;
#pragma unroll
    for (int ds = 0; ds < 4; ++ds)
      AOb[row * 1024 + h * 64 + ds * 16 + lo] = f32_to_bf16(oacc[ds][r] * inv_l);
  }
}

// ---------------------------------------------------------------------------
// Kernel 4: output projection with fp32 bias, fp32 output.  grid (64, 16).
// ---------------------------------------------------------------------------
__global__ void __launch_bounds__(256) out_gemm(
    const u16* __restrict__ A, const u16* __restrict__ WoT,
    const float* __restrict__ bias, float* __restrict__ C) {
  __shared__ u16 As[2 * 64 * 64];
  __shared__ u16 Bs[2 * 64 * 64];
  int tid = threadIdx.x, lane = tid & 63, w = tid >> 6;
  int wr = w >> 1, wc = w & 1, g = lane >> 4, lo = lane & 15;
  int m0 = blockIdx.x * 64, nb = blockIdx.y;
  const u16* BT = WoT + (size_t)nb * 64 * 1024;
  f32x4 acc[2][2];
  f32x4 zz = {0.f, 0.f, 0.f, 0.f};
#pragma unroll
  for (int i = 0; i < 2; ++i)
#pragma unroll
    for (int j = 0; j < 2; ++j) acc[i][j] = zz;
  gemm_core_64_db(A, BT, m0, 1024, acc, As, Bs, lane, w, wr, wc, g, lo);
#pragma unroll
  for (int mi = 0; mi < 2; ++mi)
#pragma unroll
    for (int ni = 0; ni < 2; ++ni)
#pragma unroll
      for (int r = 0; r < 4; ++r) {
        int row = m0 + wr * 32 + mi * 16 + g * 4 + r;
        int col = nb * 64 + wc * 32 + ni * 16 + lo;
        C[row * 1024 + col] = acc[mi][ni][r] + bias[col];
      }
}

// ---------------------------------------------------------------------------
extern "C" void kernel_launch(void* const* d_in, const int* in_sizes, int n_in,
                              void* d_out, int out_size, void* d_ws, size_t ws_size,
                              hipStream_t stream) {
  const float* x  = (const float*)d_in[0];
  const float* Wq = (const float*)d_in[1];
  const float* Wk = (const float*)d_in[2];
  const float* Wv = (const float*)d_in[3];
  const float* Wo = (const float*)d_in[4];
  const float* bo = (const float*)d_in[5];
  float* out = (float*)d_out;

  // bf16 Q scratch lives in d_out (fp32 16.8 MB; Q needs 8 MB, dead before
  // out_gemm overwrites).  ws: AOb | KVb | VTb | Xb | WqT | WoT | WkvT ~21 MB
  u16* ws   = (u16*)d_ws;
  u16* AOb  = ws;                    // 4096*1024
  u16* KVb  = AOb + 4194304;         // 4096*64   (K only, compact)
  u16* VTb  = KVb + 262144;          // 2*64*2048 (V transposed)
  u16* Xb   = VTb + 262144;          // 4096*1024
  u16* WqT  = Xb + 4194304;          // 1024*1024
  u16* WoT  = WqT + 1048576;         // 1024*1024
  u16* WkvT = WoT + 1048576;         // 128*1024
  u16* Qb   = (u16*)d_out;           // 4096*1024 bf16 (scratch phase)

  prep_kernel<<<2592, 256, 0, stream>>>(x, Wq, Wk, Wv, Wo, Xb, WqT, WkvT, WoT);
  qkv_gemm<<<dim3(64, 18), 256, 0, stream>>>(Xb, WqT, WkvT, Qb, KVb, VTb);
  attn_kernel<<<dim3(16, 32, 2), 256, 0, stream>>>(Qb, KVb, VTb, AOb);
  out_gemm<<<dim3(64, 16), 256, 0, stream>>>(AOb, WoT, bo, out);
}

// Round 11
// 163.971 us; speedup vs baseline: 1.0626x; 1.0626x over previous
//
#include <hip/hip_runtime.h>

typedef unsigned short u16;
typedef __attribute__((ext_vector_type(8))) short short8;   // 8 bf16 = 4 VGPRs (MFMA A/B frag)
typedef __attribute__((ext_vector_type(4))) float f32x4;    // MFMA C/D frag

static __device__ __forceinline__ u16 f32_to_bf16(float f) {
  unsigned u = __float_as_uint(f);
  u += 0x7fffu + ((u >> 16) & 1u);   // round-to-nearest-even; inputs finite
  return (u16)(u >> 16);
}

// async global->LDS, 16 B per lane; lds base must be wave-uniform, lane i
// lands at base + i*16 (m97/m104 semantics).
static __device__ __forceinline__ void async16(u16* lds, const u16* g) {
  __builtin_amdgcn_global_load_lds(
      (const __attribute__((address_space(1))) void*)g,
      (__attribute__((address_space(3))) void*)lds, 16, 0, 0);
}

// XOR-swizzled LDS tiles: row r (8 chunks of 16B), logical chunk c at physical
// c ^ (r&7).  Staging lane uses global chunk (lane&7)^(lane>>3); reads XOR the
// chunk index with lo&7.  Conflict-free (R6-verified: 1.35e7 -> 5.4e5).

// ---------------------------------------------------------------------------
// Kernel 0 (merged prep): id<2048 -> fp32->bf16 convert of x (8 elem/thread);
// id>=2048 -> weight transpose+convert.
// ---------------------------------------------------------------------------
__global__ void __launch_bounds__(256) prep_kernel(
    const float* __restrict__ x,
    const float* __restrict__ Wq, const float* __restrict__ Wk,
    const float* __restrict__ Wv, const float* __restrict__ Wo,
    u16* __restrict__ Xb, u16* __restrict__ WqT, u16* __restrict__ WkvT,
    u16* __restrict__ WoT) {
  __shared__ u16 T[64][72];
  int id = blockIdx.x;
  int tid = threadIdx.x;
  if (id < 2048) {                       // convert role
    int base = (id * 256 + tid) * 8;
    float4 a = *(const float4*)&x[base];
    float4 b = *(const float4*)&x[base + 4];
    short8 v;
    v[0] = (short)f32_to_bf16(a.x); v[1] = (short)f32_to_bf16(a.y);
    v[2] = (short)f32_to_bf16(a.z); v[3] = (short)f32_to_bf16(a.w);
    v[4] = (short)f32_to_bf16(b.x); v[5] = (short)f32_to_bf16(b.y);
    v[6] = (short)f32_to_bf16(b.z); v[7] = (short)f32_to_bf16(b.w);
    *(short8*)&Xb[base] = v;
    return;
  }
  int id2 = id - 2048;                   // transpose role, 0..543
  const float* src; u16* dst; int tk, tn, src_ld, row_off;
  if (id2 < 256)      { src = Wq; dst = WqT;  tk = id2 & 15; tn = id2 >> 4; src_ld = 1024; row_off = 0; }
  else if (id2 < 512) { int i = id2 - 256; src = Wo; dst = WoT; tk = i & 15; tn = i >> 4; src_ld = 1024; row_off = 0; }
  else if (id2 < 528) { src = Wk; dst = WkvT; tk = id2 - 512; tn = 0; src_ld = 64; row_off = 0; }
  else                { src = Wv; dst = WkvT; tk = id2 - 528; tn = 0; src_ld = 64; row_off = 64; }
  int k0 = tk * 64, n0 = tn * 64;
#pragma unroll
  for (int it = 0; it < 2; ++it) {
    int c = tid + it * 256;            // 0..511
    int r = c >> 3, cc = (c & 7) * 8;  // src row (k), col chunk (n)
    const float* p = &src[(k0 + r) * src_ld + n0 + cc];
    float4 a = *(const float4*)&p[0];
    float4 b = *(const float4*)&p[4];
    short8 v;
    v[0] = (short)f32_to_bf16(a.x); v[1] = (short)f32_to_bf16(a.y);
    v[2] = (short)f32_to_bf16(a.z); v[3] = (short)f32_to_bf16(a.w);
    v[4] = (short)f32_to_bf16(b.x); v[5] = (short)f32_to_bf16(b.y);
    v[6] = (short)f32_to_bf16(b.z); v[7] = (short)f32_to_bf16(b.w);
    *(short8*)&T[r][cc] = v;
  }
  __syncthreads();
#pragma unroll
  for (int it = 0; it < 2; ++it) {
    int c = tid + it * 256;
    int r = c >> 3, cc = (c & 7) * 8;  // dst row (n), col chunk (k)
    short8 v;
#pragma unroll
    for (int j = 0; j < 8; ++j) v[j] = (short)T[cc + j][r];
    *(short8*)&dst[(row_off + n0 + r) * 1024 + k0 + cc] = v;
  }
}

// ---------------------------------------------------------------------------
// GEMM 64x128 tile, BK=64, 4 waves, double-buffered single-barrier K-loop
// (exact R8 core — best measured GEMM config: 576/512-block grids, 2.25/CU).
// ---------------------------------------------------------------------------
__device__ __forceinline__ void stage_64x128(
    const u16* __restrict__ A, const u16* __restrict__ BT, int m0, int K,
    int k0, u16* As, u16* Bs, int w, int lrow, int swz8) {
#pragma unroll
  for (int it = 0; it < 2; ++it) {           // A: 8 chunk-groups (64 rows)
    int W = w * 2 + it;
    async16(As + W * 512, &A[(size_t)(m0 + W * 8 + lrow) * K + k0 + swz8]);
  }
#pragma unroll
  for (int it = 0; it < 4; ++it) {           // B: 16 chunk-groups (128 rows)
    int W = w * 4 + it;
    async16(Bs + W * 512, &BT[(size_t)(W * 8 + lrow) * K + k0 + swz8]);
  }
}

__device__ __forceinline__ void gemm_core_64x128_db(
    const u16* __restrict__ A, const u16* __restrict__ BT, int m0, int K,
    f32x4 (&acc)[2][4], u16* As, u16* Bs,   // As: 2 x 64*64, Bs: 2 x 128*64
    int lane, int w, int wr, int wc, int g, int lo) {
  int lrow = lane >> 3;
  int swz8 = ((lane & 7) ^ lrow) * 8;
  int lo7 = lo & 7;
  const int NK = K >> 6;
  stage_64x128(A, BT, m0, K, 0, As, Bs, w, lrow, swz8);
  for (int kt = 0; kt < NK; ++kt) {
    int cur = kt & 1;
    __syncthreads();                         // cur buf ready; nxt buf free
    if (kt + 1 < NK)
      stage_64x128(A, BT, m0, K, (kt + 1) * 64,
                   As + (cur ^ 1) * 4096, Bs + (cur ^ 1) * 8192, w, lrow, swz8);
    const u16* Asc = As + cur * 4096;
    const u16* Bsc = Bs + cur * 8192;
#pragma unroll
    for (int ks = 0; ks < 2; ++ks) {
      int pc = ((ks * 4 + g) ^ lo7) * 8;     // physical chunk offset
      short8 af[2], bf[4];
#pragma unroll
      for (int i = 0; i < 2; ++i)
        af[i] = *(const short8*)&Asc[(wr * 32 + i * 16 + lo) * 64 + pc];
#pragma unroll
      for (int i = 0; i < 4; ++i)
        bf[i] = *(const short8*)&Bsc[(wc * 64 + i * 16 + lo) * 64 + pc];
#pragma unroll
      for (int mi = 0; mi < 2; ++mi)
#pragma unroll
        for (int ni = 0; ni < 4; ++ni)
          acc[mi][ni] = __builtin_amdgcn_mfma_f32_16x16x32_bf16(
              af[mi], bf[ni], acc[mi][ni], 0, 0, 0);
    }
  }
}

// ---------------------------------------------------------------------------
// Kernel 2: QKV projection.  grid (64, 9).  nb<8: Q tile into Qb [4096][1024]
// (UNSCALED; Qb = d_out scratch).  nb==8: K into KVb [4096][64] compact;
// V scattered transposed into VTb [2][64][2048].
// ---------------------------------------------------------------------------
__global__ void __launch_bounds__(256) qkv_gemm(
    const u16* __restrict__ Xb, const u16* __restrict__ WqT,
    const u16* __restrict__ WkvT, u16* __restrict__ Qb, u16* __restrict__ KVb,
    u16* __restrict__ VTb) {
  __shared__ u16 As[2 * 64 * 64];
  __shared__ u16 Bs[2 * 128 * 64];
  int tid = threadIdx.x, lane = tid & 63, w = tid >> 6;
  int wr = w >> 1, wc = w & 1, g = lane >> 4, lo = lane & 15;
  int m0 = blockIdx.x * 64, nb = blockIdx.y;
  const u16* BT = (nb < 8) ? (WqT + (size_t)nb * 128 * 1024) : WkvT;
  f32x4 acc[2][4];
  f32x4 zz = {0.f, 0.f, 0.f, 0.f};
#pragma unroll
  for (int i = 0; i < 2; ++i)
#pragma unroll
    for (int j = 0; j < 4; ++j) acc[i][j] = zz;
  gemm_core_64x128_db(Xb, BT, m0, 1024, acc, As, Bs, lane, w, wr, wc, g, lo);
#pragma unroll
  for (int mi = 0; mi < 2; ++mi)
#pragma unroll
    for (int ni = 0; ni < 4; ++ni)
#pragma unroll
      for (int r = 0; r < 4; ++r) {
        int row = m0 + wr * 32 + mi * 16 + g * 4 + r;
        int col = wc * 64 + ni * 16 + lo;
        u16 v = f32_to_bf16(acc[mi][ni][r]);
        if (nb < 8) {
          Qb[row * 1024 + nb * 128 + col] = v;
        } else if (wc == 0) {
          KVb[row * 64 + col] = v;                   // K half, compact stride 64
        } else {
          int d = col - 64;                          // V: scatter transposed
          VTb[(((row >> 11) * 64) + d) * 2048 + (row & 2047)] = v;
        }
      }
}

// ---------------------------------------------------------------------------
// Kernel 3: fused causal flash attention (MQA), 8 waves / 512 threads, BQ=128
// (16 q-rows per wave).  grid (16 h, 16 by, 2 z) = 512 blocks = 2/CU exact
// -> 16 waves/CU (vs 12 at 4-wave blocks); K/V staged once per 128 q-rows
// (staging bytes and barriers per unit work halved).  z-aware swizzle
// qt = z ? 15-by : by keeps co-resident pair (id, id+256) complementary.
// Double-buffered single-barrier KV loop; fixed-offset softmax
// p = exp2(s*0.125*log2e - 11.5416) (shift-invariant, no overflow: scores
// ~N(0,1)); row-sum l via all-ones-B MFMA; Ps stored by truncation.
// ---------------------------------------------------------------------------
__global__ void __launch_bounds__(512) attn_kernel(
    const u16* __restrict__ Qb, const u16* __restrict__ KVb,
    const u16* __restrict__ VTb, u16* __restrict__ AOb) {
  __shared__ u16 Ks[2][64 * 64];    // K tile [key][d], swizzled (16 KB)
  __shared__ u16 Vt[2][64 * 64];    // V tile [d][key], swizzled (16 KB)
  __shared__ u16 Ps[8][16][72];     // per-wave P [q_local][key], padded (18 KB)
  int tid = threadIdx.x, lane = tid & 63, w = tid >> 6;   // w = 0..7
  int gq = lane >> 4, lo = lane & 15;
  int h = blockIdx.x;
  int by = blockIdx.y;                      // 0..15
  int z = blockIdx.z;
  int b = z;
  int qt = z ? (15 - by) : by;              // co-resident pair balanced
  int q0 = qt * 128;
  int qbase = q0 + w * 16;                  // this wave's first q-row
  int lrow = lane >> 3;
  int swz8 = ((lane & 7) ^ lrow) * 8;
  int lo7 = lo & 7;

  // Q fragments (A-layout): row = lo, k = ks*32 + gq*8 + j
  short8 qf[2];
  {
    const u16* qp = &Qb[(size_t)(b * 2048 + qbase + lo) * 1024 + h * 64];
    qf[0] = *(const short8*)&qp[gq * 8];
    qf[1] = *(const short8*)&qp[32 + gq * 8];
  }

  short8 ones;
#pragma unroll
  for (int j = 0; j < 8; ++j) ones[j] = (short)0x3F80;  // bf16 1.0

  f32x4 zz = {0.f, 0.f, 0.f, 0.f};
  f32x4 oacc[4], l_acc;
#pragma unroll
  for (int i = 0; i < 4; ++i) oacc[i] = zz;
  l_acc = zz;

  const float kExp = 0.18033688011112042f;   // 0.125*log2(e)
  const float kOff = 11.541560327111707f;    // 8*log2(e) fixed offset

  // stage tile t into buffer bu: 8 chunk-groups each, one per wave
  auto stage_kv = [&](int t, int bu) {
    async16(&Ks[bu][w * 512],
            &KVb[(size_t)(b * 2048 + t * 64 + w * 8 + lrow) * 64 + swz8]);
    async16(&Vt[bu][w * 512],
            &VTb[((size_t)b * 64 + w * 8 + lrow) * 2048 + t * 64 + swz8]);
  };

  int nst = 2 * qt + 2;   // causal: keys 0 .. q0+127
  stage_kv(0, 0);
  for (int t = 0; t < nst; ++t) {
    int cur = t & 1;
    __syncthreads();                 // cur ready; nxt free
    if (t + 1 < nst) stage_kv(t + 1, cur ^ 1);
    int k0 = t * 64;

    // S_raw = Q @ K^T
    f32x4 sacc[4];
#pragma unroll
    for (int ns = 0; ns < 4; ++ns) sacc[ns] = zz;
#pragma unroll
    for (int ks = 0; ks < 2; ++ks) {
      int pc = ((ks * 4 + gq) ^ lo7) * 8;
      short8 kf[4];
#pragma unroll
      for (int ns = 0; ns < 4; ++ns)
        kf[ns] = *(const short8*)&Ks[cur][(ns * 16 + lo) * 64 + pc];
#pragma unroll
      for (int ns = 0; ns < 4; ++ns)
        sacc[ns] = __builtin_amdgcn_mfma_f32_16x16x32_bf16(
            qf[ks], kf[ns], sacc[ns], 0, 0, 0);
    }

    // p = exp2(s*kExp - kOff); causal mask p=0 where key > query
    bool diag = (k0 + 63) > qbase;
#pragma unroll
    for (int ns = 0; ns < 4; ++ns)
#pragma unroll
      for (int r = 0; r < 4; ++r) {
        float p = __builtin_amdgcn_exp2f(fmaf(sacc[ns][r], kExp, -kOff));
        if (diag) {
          int qg = qbase + gq * 4 + r;
          int kg = k0 + ns * 16 + lo;
          if (kg > qg) p = 0.f;
        }
        Ps[w][gq * 4 + r][ns * 16 + lo] = (u16)(__float_as_uint(p) >> 16);
      }
    __threadfence_block();   // wave-private Ps: lgkm wait, no block barrier

    // O += P @ V ; l += P @ 1
#pragma unroll
    for (int k2 = 0; k2 < 2; ++k2) {
      short8 pf = *(const short8*)&Ps[w][lo][k2 * 32 + gq * 8];
      int pc = ((k2 * 4 + gq) ^ lo7) * 8;
      short8 vf[4];
#pragma unroll
      for (int ds = 0; ds < 4; ++ds)
        vf[ds] = *(const short8*)&Vt[cur][(ds * 16 + lo) * 64 + pc];
#pragma unroll
      for (int ds = 0; ds < 4; ++ds)
        oacc[ds] = __builtin_amdgcn_mfma_f32_16x16x32_bf16(
            pf, vf[ds], oacc[ds], 0, 0, 0);
      l_acc = __builtin_amdgcn_mfma_f32_16x16x32_bf16(pf, ones, l_acc, 0, 0, 0);
    }
  }

  // epilogue: normalize and store [s][h*64+d] bf16
#pragma unroll
  for (int r = 0; r < 4; ++r) {
    float inv_l = 1.0f / l_acc[r];
    int row = b * 2048 + qbase + gq * 4 + r;
#pragma unroll
    for (int ds = 0; ds < 4; ++ds)
      AOb[row * 1024 + h * 64 + ds * 16 + lo] = f32_to_bf16(oacc[ds][r] * inv_l);
  }
}

// ---------------------------------------------------------------------------
// Kernel 4: output projection with fp32 bias, fp32 output.  grid (64, 8).
// ---------------------------------------------------------------------------
__global__ void __launch_bounds__(256) out_gemm(
    const u16* __restrict__ A, const u16* __restrict__ WoT,
    const float* __restrict__ bias, float* __restrict__ C) {
  __shared__ u16 As[2 * 64 * 64];
  __shared__ u16 Bs[2 * 128 * 64];
  int tid = threadIdx.x, lane = tid & 63, w = tid >> 6;
  int wr = w >> 1, wc = w & 1, g = lane >> 4, lo = lane & 15;
  int m0 = blockIdx.x * 64, nb = blockIdx.y;
  const u16* BT = WoT + (size_t)nb * 128 * 1024;
  f32x4 acc[2][4];
  f32x4 zz = {0.f, 0.f, 0.f, 0.f};
#pragma unroll
  for (int i = 0; i < 2; ++i)
#pragma unroll
    for (int j = 0; j < 4; ++j) acc[i][j] = zz;
  gemm_core_64x128_db(A, BT, m0, 1024, acc, As, Bs, lane, w, wr, wc, g, lo);
#pragma unroll
  for (int mi = 0; mi < 2; ++mi)
#pragma unroll
    for (int ni = 0; ni < 4; ++ni)
#pragma unroll
      for (int r = 0; r < 4; ++r) {
        int row = m0 + wr * 32 + mi * 16 + g * 4 + r;
        int col = nb * 128 + wc * 64 + ni * 16 + lo;
        C[row * 1024 + col] = acc[mi][ni][r] + bias[col];
      }
}

// ---------------------------------------------------------------------------
extern "C" void kernel_launch(void* const* d_in, const int* in_sizes, int n_in,
                              void* d_out, int out_size, void* d_ws, size_t ws_size,
                              hipStream_t stream) {
  const float* x  = (const float*)d_in[0];
  const float* Wq = (const float*)d_in[1];
  const float* Wk = (const float*)d_in[2];
  const float* Wv = (const float*)d_in[3];
  const float* Wo = (const float*)d_in[4];
  const float* bo = (const float*)d_in[5];
  float* out = (float*)d_out;

  // bf16 Q scratch lives in d_out (fp32 16.8 MB; Q needs 8 MB, dead before
  // out_gemm overwrites).  ws: AOb | KVb | VTb | Xb | WqT | WoT | WkvT ~21 MB
  u16* ws   = (u16*)d_ws;
  u16* AOb  = ws;                    // 4096*1024
  u16* KVb  = AOb + 4194304;         // 4096*64   (K only, compact)
  u16* VTb  = KVb + 262144;          // 2*64*2048 (V transposed)
  u16* Xb   = VTb + 262144;          // 4096*1024
  u16* WqT  = Xb + 4194304;          // 1024*1024
  u16* WoT  = WqT + 1048576;         // 1024*1024
  u16* WkvT = WoT + 1048576;         // 128*1024
  u16* Qb   = (u16*)d_out;           // 4096*1024 bf16 (scratch phase)

  prep_kernel<<<2592, 256, 0, stream>>>(x, Wq, Wk, Wv, Wo, Xb, WqT, WkvT, WoT);
  qkv_gemm<<<dim3(64, 9), 256, 0, stream>>>(Xb, WqT, WkvT, Qb, KVb, VTb);
  attn_kernel<<<dim3(16, 16, 2), 512, 0, stream>>>(Qb, KVb, VTb, AOb);
  out_gemm<<<dim3(64, 8), 256, 0, stream>>>(AOb, WoT, bo, out);
}